// Round 12
// baseline (332.848 us; speedup 1.0000x reference)
//
#include <hip/hip_runtime.h>
#include <math.h>

#define DM    1024
#define NH    16
#define DH    64
#define DI    4096
#define QL    1024
#define MLN   1024
#define BATCH 2
#define KL    2048   // QL + MLN
#define RPAD  2304   // padded jj extent for rh / rb2

// attention scale folded with log2(e) so softmax uses raw v_exp_f32 (2^x)
#define SCALE_LOG2E 0.18033688011112042f   // 0.125 * log2(e)

typedef unsigned short u16;
typedef short s16x8 __attribute__((ext_vector_type(8)));
typedef float f32x4 __attribute__((ext_vector_type(4)));

#if __has_builtin(__builtin_amdgcn_exp2f)
#define EXP2(x) __builtin_amdgcn_exp2f(x)
#else
#define EXP2(x) __expf((x) * 0.6931471805599453f)
#endif

__device__ __forceinline__ u16 f2bf(float f) {
    union { float f; unsigned u; } v; v.f = f;
    unsigned u = v.u;
    unsigned r = (u + 0x7FFFu + ((u >> 16) & 1u)) >> 16;
    return (u16)r;
}
__device__ __forceinline__ u16 f2bf_fast(float f) {
    union { float f; unsigned u; } v; v.f = f;
    return (u16)((v.u + 0x8000u) >> 16);
}
__device__ __forceinline__ float bf2f(u16 h) {
    union { unsigned u; float f; } v; v.u = ((unsigned)h) << 16;
    return v.f;
}

__device__ __forceinline__ void gl2lds16(const void* g, void* l) {
    __builtin_amdgcn_global_load_lds(
        (const __attribute__((address_space(1))) void*)g,
        (__attribute__((address_space(3))) void*)l, 16, 0, 0);
}

// ---------------- fused weight fp32->bf16 (one launch) ----------------
__global__ __launch_bounds__(256) void cvt_multi(
    const float* __restrict__ a0, const float* __restrict__ a1,
    const float* __restrict__ a2, const float* __restrict__ a3,
    u16* __restrict__ o0, u16* __restrict__ o1,
    u16* __restrict__ o2, u16* __restrict__ o3) {
    int i = blockIdx.x * 256 + threadIdx.x;
    int stride = gridDim.x * 256;
    for (; i < 3145728; i += stride) {
        const float* src; u16* dst; int k;
        if (i < 786432)       { src = a0; dst = o0; k = i; }
        else if (i < 1048576) { src = a1; dst = o1; k = i - 786432; }
        else if (i < 2097152) { src = a2; dst = o2; k = i - 1048576; }
        else                  { src = a3; dst = o3; k = i - 2097152; }
        float4 v = ((const float4*)src)[k];
        ushort4 o = {f2bf(v.x), f2bf(v.y), f2bf(v.z), f2bf(v.w)};
        ((ushort4*)dst)[k] = o;
    }
}

// rh[n][jj][64d], granule-swizzled: stored granule gs holds logical granule
// gl=(gs-jj)&7 (16B granules). jj>=KL -> zeros. grid dim3(72,16).
__global__ __launch_bounds__(256) void rcvt(const float* __restrict__ r_emb,
                                            u16* __restrict__ rh) {
    int id = blockIdx.x * 256 + threadIdx.x;
    int n = blockIdx.y;
    int jj = id >> 3, gs = id & 7;
    s16x8 o;
    if (jj < KL) {
        int gl = (gs - jj) & 7;
        const float* s = r_emb + (size_t)jj * DM + n * 64 + gl * 8;
#pragma unroll
        for (int k = 0; k < 8; ++k) o[k] = (short)f2bf(s[k]);
    } else {
#pragma unroll
        for (int k = 0; k < 8; ++k) o[k] = 0;
    }
    *(s16x8*)(rh + ((size_t)n * RPAD + jj) * 64 + gs * 8) = o;
}

// rb2[n][jj] = SCALE_LOG2E*(r_bias[jj,n] - r_w_bias[n,:].dot(r_emb[jj,n,:])), padded.
__global__ __launch_bounds__(256) void rb2_prep(const float* __restrict__ r_emb,
                                                const float* __restrict__ r_w_bias,
                                                const float* __restrict__ r_bias,
                                                float* __restrict__ rb2) {
    int jj = blockIdx.x * 256 + threadIdx.x;
    int n = blockIdx.y;
    if (jj >= RPAD) return;
    float v = 0.0f;
    if (jj < KL) {
        float dot = 0.0f;
#pragma unroll 8
        for (int d = 0; d < 64; ++d)
            dot += r_w_bias[n * 64 + d] * r_emb[(size_t)jj * DM + n * 64 + d];
        v = SCALE_LOG2E * (r_bias[jj * NH + n] - dot);
    }
    rb2[n * RPAD + jj] = v;
}

// ---------------- staged GEMM: C[M,*] = A[M,K] * B[*,K]^T ----------------
// T3-minimum 2-phase pipeline — double-buffered As/Bs, stage(t+1) issued
// BEFORE compute(t), ONE barrier per K-step. Staging hides under MFMA work.
// FLAGS: 1=bf16 out, 2=bias, 4=relu, 8=QKV split epilogue (Q/Kh/Vt2 layouts),
//        16=fused-cvt A: stage A by reg-loading fp32 from mems/w (cat layout,
//        row = b*2048+kpos) + f2bf + ds_write into the IDENTICAL LDS layout
//        gl2lds produced. Kills the cvt_cat pre-pass; bits identical.
template <int BN, int FLAGS>
__global__ __launch_bounds__(256) void gemm_s(const u16* __restrict__ A,
                                              const u16* __restrict__ B,
                                              float* __restrict__ Cf,
                                              u16* __restrict__ Cb,
                                              u16* __restrict__ Qo,
                                              u16* __restrict__ Ko,
                                              u16* __restrict__ Vo,
                                              const float* __restrict__ bias,
                                              const float* __restrict__ Amems,
                                              const float* __restrict__ Aw,
                                              int M, int N_out, int K) {
    constexpr int WN = BN / 2;
    constexpr int TN = WN / 16;

    if constexpr (FLAGS & 8) {
        // dead-block skip: Q columns (n_blk<8) x mems rows ((y&15)<8) store
        // nothing -> 128/768 blocks, -16.7%.
        if (blockIdx.x < 8 && (blockIdx.y & 15) < 8) return;
    }

    __shared__ u16 As[2][128 * 32];
    __shared__ u16 Bs[2][BN * 32];

    const int t = threadIdx.x;
    const int lane = t & 63, wid = t >> 6;
    const int wm = wid >> 1, wn = wid & 1;
    const int lr = lane & 15, quad = lane >> 4;
    const int m_blk = blockIdx.y * 128;
    const int n_blk = blockIdx.x * BN;
    const int srow = t >> 2;
    const int skc  = (t & 3) * 8;

    f32x4 acc[4][TN];
#pragma unroll
    for (int i = 0; i < 4; ++i)
#pragma unroll
        for (int j = 0; j < TN; ++j) acc[i][j] = (f32x4)0.0f;

    // fp32 A source pointer for cat-layout row rg (FLAGS&16 only)
    auto srcA = [&](int rg) -> const float* {
        int bb = rg >> 11, kp = rg & 2047;
        return (kp < QL) ? Amems + ((size_t)kp * BATCH + bb) * DM
                         : Aw + ((size_t)(kp - QL) * BATCH + bb) * DM;
    };

    // prefetched fp32 A (2 rows x 32B), live across the MFMA block
    float4 a0l, a0h, a1l, a1h;
    auto issueA = [&](int k0) {
        if constexpr (FLAGS & 16) {
            const float* s0 = srcA(m_blk + srow) + k0 + skc;
            const float* s1 = srcA(m_blk + 64 + srow) + k0 + skc;
            a0l = *(const float4*)s0;       a0h = *(const float4*)(s0 + 4);
            a1l = *(const float4*)s1;       a1h = *(const float4*)(s1 + 4);
        }
    };
    auto commitA = [&](int bf) {
        if constexpr (FLAGS & 16) {
            s16x8 v0, v1;
            v0[0] = (short)f2bf(a0l.x); v0[1] = (short)f2bf(a0l.y);
            v0[2] = (short)f2bf(a0l.z); v0[3] = (short)f2bf(a0l.w);
            v0[4] = (short)f2bf(a0h.x); v0[5] = (short)f2bf(a0h.y);
            v0[6] = (short)f2bf(a0h.z); v0[7] = (short)f2bf(a0h.w);
            v1[0] = (short)f2bf(a1l.x); v1[1] = (short)f2bf(a1l.y);
            v1[2] = (short)f2bf(a1l.z); v1[3] = (short)f2bf(a1l.w);
            v1[4] = (short)f2bf(a1h.x); v1[5] = (short)f2bf(a1h.y);
            v1[6] = (short)f2bf(a1h.z); v1[7] = (short)f2bf(a1h.w);
            *(s16x8*)(&As[bf][srow * 32 + skc]) = v0;
            *(s16x8*)(&As[bf][(64 + srow) * 32 + skc]) = v1;
        }
    };

    auto stage = [&](int bf, int k0) {
        if constexpr (!(FLAGS & 16)) {
            gl2lds16(A + (size_t)(m_blk + srow) * K + k0 + skc, &As[bf][wid * 512]);
            gl2lds16(A + (size_t)(m_blk + 64 + srow) * K + k0 + skc, &As[bf][2048 + wid * 512]);
        }
        gl2lds16(B + (size_t)(n_blk + srow) * K + k0 + skc, &Bs[bf][wid * 512]);
        if (BN == 128)
            gl2lds16(B + (size_t)(n_blk + 64 + srow) * K + k0 + skc, &Bs[bf][2048 + wid * 512]);
    };

    issueA(0);
    commitA(0);          // one exposed fp32-load wait, prologue only
    stage(0, 0);
    __syncthreads();     // drains vmcnt + lgkm: buf0 staged

    int cur = 0;
    for (int k0 = 0; k0 < K; k0 += 32) {
        if (k0 + 32 < K) { issueA(k0 + 32); stage(cur ^ 1, k0 + 32); }

        s16x8 a[4], b[TN];
#pragma unroll
        for (int i = 0; i < 4; ++i)
            a[i] = *(const s16x8*)(&As[cur][(wm * 64 + i * 16 + lr) * 32 + quad * 8]);
#pragma unroll
        for (int j = 0; j < TN; ++j)
            b[j] = *(const s16x8*)(&Bs[cur][(wn * WN + j * 16 + lr) * 32 + quad * 8]);
#pragma unroll
        for (int i = 0; i < 4; ++i)
#pragma unroll
            for (int j = 0; j < TN; ++j)
                acc[i][j] = __builtin_amdgcn_mfma_f32_16x16x32_bf16(
                    a[i], b[j], acc[i][j], 0, 0, 0);

        if (k0 + 32 < K) commitA(cur ^ 1);   // fp32 waits hidden under MFMA

        __syncthreads();   // staging(t+1) landed; all waves done with buf[cur]
        cur ^= 1;
    }

#pragma unroll
    for (int i = 0; i < 4; ++i) {
#pragma unroll
        for (int j = 0; j < TN; ++j) {
            int row0 = m_blk + wm * 64 + i * 16 + quad * 4;
            int col  = n_blk + wn * WN + j * 16 + lr;
            if (FLAGS & 8) {
                int b_ = row0 >> 11, kpos = row0 & 2047;
                if (col < 1024) {
                    if (kpos >= QL) {
                        u16* q = Qo + ((size_t)(b_ * QL + kpos - QL)) * 1024 + col;
#pragma unroll
                        for (int r = 0; r < 4; ++r) q[r * 1024] = f2bf(acc[i][j][r]);
                    }
                } else if (col < 2048) {
                    int d = col & 63, nh = (col >> 6) & 15;
                    size_t base = ((size_t)((b_ * 16 + nh) * 16 + (kpos >> 7))) * 8192;
#pragma unroll
                    for (int r = 0; r < 4; ++r) {
                        int jl = (kpos & 127) + r;
                        Ko[base + jl * 64 + (((d >> 3) + jl) & 7) * 8 + (d & 7)] =
                            f2bf(acc[i][j][r]);
                    }
                } else {
                    int d = col & 63, nh = (col >> 6) & 15;
                    int jl = kpos & 127;
                    size_t base = ((size_t)((b_ * 16 + nh) * 16 + (kpos >> 7))) * 8192
                                  + d * 128 + (((jl >> 3) + d) & 15) * 8 + (jl & 7);
                    ushort4 o = {f2bf(acc[i][j][0]), f2bf(acc[i][j][1]),
                                 f2bf(acc[i][j][2]), f2bf(acc[i][j][3])};
                    *(ushort4*)(Vo + base) = o;
                }
            } else {
                float bv = (FLAGS & 2) ? bias[col] : 0.0f;
#pragma unroll
                for (int r = 0; r < 4; ++r) {
                    float v = acc[i][j][r] + bv;
                    if (FLAGS & 4) v = fmaxf(v, 0.0f);
                    size_t idx = (size_t)(row0 + r) * N_out + col;
                    if (FLAGS & 1) Cb[idx] = f2bf(v);
                    else           Cf[idx] = v;
                }
            }
        }
    }
}

// ---------------- split-K GEMM: P[kz][M,N] = A[M,Kc] * B[N,Kc]^T ----------------
// Same 2-phase double-buffer as gemm_s. grid (N/64, M/128, SPLIT).
template <int SPLIT>
__global__ __launch_bounds__(256) void gemm_sk(const u16* __restrict__ A,
                                               const u16* __restrict__ B,
                                               float* __restrict__ P,
                                               int M, int N_out, int K) {
    __shared__ u16 As[2][128 * 32];
    __shared__ u16 Bs[2][64 * 32];

    const int t = threadIdx.x;
    const int lane = t & 63, wid = t >> 6;
    const int wm = wid >> 1, wn = wid & 1;
    const int lr = lane & 15, quad = lane >> 4;
    const int m_blk = blockIdx.y * 128;
    const int n_blk = blockIdx.x * 64;
    const int kz = blockIdx.z;
    const int Kc = K / SPLIT;
    const int kbeg = kz * Kc, kend = kbeg + Kc;
    const int srow = t >> 2;
    const int skc  = (t & 3) * 8;

    f32x4 acc[4][2];
#pragma unroll
    for (int i = 0; i < 4; ++i)
#pragma unroll
        for (int j = 0; j < 2; ++j) acc[i][j] = (f32x4)0.0f;

    auto stage = [&](int bf, int k0) {
        gl2lds16(A + (size_t)(m_blk + srow) * K + k0 + skc, &As[bf][wid * 512]);
        gl2lds16(A + (size_t)(m_blk + 64 + srow) * K + k0 + skc, &As[bf][2048 + wid * 512]);
        gl2lds16(B + (size_t)(n_blk + srow) * K + k0 + skc, &Bs[bf][wid * 512]);
    };

    stage(0, kbeg);
    __syncthreads();

    int cur = 0;
    for (int k0 = kbeg; k0 < kend; k0 += 32) {
        if (k0 + 32 < kend) stage(cur ^ 1, k0 + 32);

        s16x8 a[4], b[2];
#pragma unroll
        for (int i = 0; i < 4; ++i)
            a[i] = *(const s16x8*)(&As[cur][(wm * 64 + i * 16 + lr) * 32 + quad * 8]);
#pragma unroll
        for (int j = 0; j < 2; ++j)
            b[j] = *(const s16x8*)(&Bs[cur][(wn * 32 + j * 16 + lr) * 32 + quad * 8]);
#pragma unroll
        for (int i = 0; i < 4; ++i)
#pragma unroll
            for (int j = 0; j < 2; ++j)
                acc[i][j] = __builtin_amdgcn_mfma_f32_16x16x32_bf16(
                    a[i], b[j], acc[i][j], 0, 0, 0);

        __syncthreads();
        cur ^= 1;
    }

    float* Pz = P + (size_t)kz * M * N_out;
#pragma unroll
    for (int i = 0; i < 4; ++i)
#pragma unroll
        for (int j = 0; j < 2; ++j) {
            int row0 = m_blk + wm * 64 + i * 16 + quad * 4;
            int col  = n_blk + wn * 32 + j * 16 + lr;
#pragma unroll
            for (int r = 0; r < 4; ++r)
                Pz[(size_t)(row0 + r) * N_out + col] = acc[i][j][r];
        }
}

// ---------------- flash attention ----------------
// BYTE-IDENTICAL to the round-8/11 kernel (57-59 µs). Staged-uniform gl2lds
// for R/K/V is the proven structure; R-direct and split-j both regressed.
__global__ __launch_bounds__(256, 2) void flash_attn(
    const u16* __restrict__ Qb, const u16* __restrict__ Kh,
    const u16* __restrict__ Vt2, const u16* __restrict__ rh,
    const float* __restrict__ r_w_bias, const float* __restrict__ rb2,
    u16* __restrict__ av) {
    const int bid = blockIdx.x;
    const int x = bid & 7;            // XCD (round-robin dispatch)
    const int s = bid >> 3;           // 0..63 sequence on this XCD
    const int half = s >> 5;          // 0/1 (CU c gets s=c and s=c+32)
    const int r_ = s & 31;
    const int bnl = (r_ >> 4) + 2 * half;   // 0..3
    const int bn = x + 8 * bnl;             // bn ≡ x (mod 8): XCD-local
    const int p_ = r_ & 15;
    const int ti = half ? (15 - p_) : p_;   // pair (p,15-p): 25 tiles/CU
    const int i0 = ti * 64;
    const int b = bn >> 4, n = bn & 15;
    const int t = threadIdx.x;
    const int lane = t & 63, w = t >> 6;
    const int lr = lane & 15, quad = lane >> 4;

    __shared__ __align__(16) u16 Ks[128 * 64];
    __shared__ __align__(16) u16 Vs[64 * 128];
    __shared__ __align__(16) u16 Rs[192 * 64];
    __shared__ __align__(16) u16 Pw_all[4 * 16 * 136];
    u16* Pw = Pw_all + w * (16 * 136);

    const int wrow0 = i0 + w * 16;

    s16x8 qw[2];
#pragma unroll
    for (int ks = 0; ks < 2; ++ks) {
        const u16* qp = Qb + ((size_t)(b * QL + wrow0 + lr)) * 1024 + n * 64 + ks * 32 + quad * 8;
        s16x8 qv = *(const s16x8*)qp;
        s16x8 o;
#pragma unroll
        for (int k = 0; k < 8; ++k) {
            float f = bf2f((u16)qv[k]) + r_w_bias[n * 64 + ks * 32 + quad * 8 + k];
            o[k] = (short)f2bf(f * SCALE_LOG2E);
        }
        qw[ks] = o;
    }

    f32x4 O[4];
    float m_r[4], l_r[4];
#pragma unroll
    for (int xx = 0; xx < 4; ++xx) {
        O[xx] = (f32x4)0.0f;
        m_r[xx] = -INFINITY;
        l_r[xx] = 0.0f;
    }

    const u16* Kt0 = Kh + (size_t)bn * 16 * 8192;
    const u16* Vt0 = Vt2 + (size_t)bn * 16 * 8192;
    const u16* Rbase = rh + (size_t)n * RPAD * 64;
    const int jend = i0 + 64 + MLN;

    // prologue: prefetch R for tile 0
    {
        const u16* Rsrc = Rbase + (size_t)(960 - i0) * 64;
#pragma unroll
        for (int k = 0; k < 6; ++k)
            gl2lds16(Rsrc + (w * 6 + k) * 512 + lane * 8, Rs + (w * 6 + k) * 512);
    }

    for (int j0 = 0; j0 < jend; j0 += 128) {
        const int jjbase_blk = j0 + 960 - i0;
        __syncthreads();   // R(t) landed; prev tile's Ks/Vs/Pw fully consumed
        {
            const u16* Ksrc = Kt0 + (size_t)(j0 >> 7) * 8192;
            const u16* Vsrc = Vt0 + (size_t)(j0 >> 7) * 8192;
#pragma unroll
            for (int k = 0; k < 4; ++k)
                gl2lds16(Ksrc + (w * 4 + k) * 512 + lane * 8, Ks + (w * 4 + k) * 512);
#pragma unroll
            for (int k = 0; k < 4; ++k)
                gl2lds16(Vsrc + (w * 4 + k) * 512 + lane * 8, Vs + (w * 4 + k) * 512);
        }

        // rel-pos term from Rs (LDS); K/V loads in flight underneath.
        f32x4 bacc[9];
#pragma unroll
        for (int c = 0; c < 9; ++c) bacc[c] = (f32x4)0.0f;
#pragma unroll
        for (int ks = 0; ks < 2; ++ks) {
#pragma unroll
            for (int c = 0; c < 9; ++c) {
                int row = c * 16 + lr + 48 - 16 * w;
                s16x8 rf = *(const s16x8*)(Rs + row * 64 + (((ks * 4 + quad) + row) & 7) * 8);
                bacc[c] = __builtin_amdgcn_mfma_f32_16x16x32_bf16(qw[ks], rf, bacc[c], 0, 0, 0);
            }
        }
#pragma unroll
        for (int c = 0; c < 9; ++c) {
            int jj = jjbase_blk + 48 - 16 * w + c * 16 + lr;
            float rv = rb2[n * RPAD + jj];
            bacc[c][0] += rv; bacc[c][1] += rv; bacc[c][2] += rv; bacc[c][3] += rv;
        }
        f32x4 sacc[8];
#pragma unroll
        for (int r = 0; r < 4; ++r) {
            int rho = quad * 4 + r;
            int lrt_src = (lr + rho + 1) & 15;
            int up = lrt_src > rho;
            int addr = (((lane & 48) | ((lr + 15 - rho) & 15)) << 2);
#pragma unroll
            for (int nt = 0; nt < 8; ++nt) {
                float v = up ? bacc[nt + 1][r] : bacc[nt][r];
                sacc[nt][r] = __int_as_float(
                    __builtin_amdgcn_ds_bpermute(addr, __float_as_int(v)));
            }
        }

        __syncthreads();   // K/V staged; all waves past bacc -> Rs dead

        // prefetch R for next tile; drains at next tile's sync1
        if (j0 + 128 < jend) {
            const u16* Rsrc = Rbase + (size_t)(jjbase_blk + 128) * 64;
#pragma unroll
            for (int k = 0; k < 6; ++k)
                gl2lds16(Rsrc + (w * 6 + k) * 512 + lane * 8, Rs + (w * 6 + k) * 512);
        }

        __builtin_amdgcn_s_setprio(1);
#pragma unroll
        for (int ks = 0; ks < 2; ++ks) {
#pragma unroll
            for (int nt = 0; nt < 8; ++nt) {
                int jloc = nt * 16 + lr;
                s16x8 kf = *(const s16x8*)(Ks + jloc * 64 + (((ks * 4 + quad) + jloc) & 7) * 8);
                sacc[nt] = __builtin_amdgcn_mfma_f32_16x16x32_bf16(qw[ks], kf, sacc[nt], 0, 0, 0);
            }
        }
        __builtin_amdgcn_s_setprio(0);

        if (j0 + 127 > i0 + MLN) {   // only the last j-tile crosses the causal edge
#pragma unroll
            for (int nt = 0; nt < 8; ++nt) {
                int j = j0 + nt * 16 + lr;
#pragma unroll
                for (int r = 0; r < 4; ++r) {
                    int i = wrow0 + quad * 4 + r;
                    if (j > i + MLN) sacc[nt][r] = -INFINITY;
                }
            }
        }

        // conservative gate: lane-local max (VALU only)
        float maxall = sacc[0][0];
#pragma unroll
        for (int nt = 0; nt < 8; ++nt)
#pragma unroll
            for (int r = 0; r < 4; ++r) maxall = fmaxf(maxall, sacc[nt][r]);
        float mmin = fminf(fminf(m_r[0], m_r[1]), fminf(m_r[2], m_r[3]));

        float mn[4];
        if (__all(maxall <= mmin + 8.0f)) {
#pragma unroll
            for (int r = 0; r < 4; ++r) mn[r] = m_r[r];
        } else {
            float mx[4];
#pragma unroll
            for (int r = 0; r < 4; ++r) {
                mx[r] = sacc[0][r];
#pragma unroll
                for (int nt = 1; nt < 8; ++nt) mx[r] = fmaxf(mx[r], sacc[nt][r]);
            }
#pragma unroll
            for (int msk = 1; msk <= 8; msk <<= 1)
#pragma unroll
                for (int r = 0; r < 4; ++r)
                    mx[r] = fmaxf(mx[r], __shfl_xor(mx[r], msk, 64));
#pragma unroll
            for (int r = 0; r < 4; ++r) {
                float t2 = fmaxf(m_r[r], mx[r]);
                float al = EXP2(m_r[r] - t2);
                m_r[r] = t2; mn[r] = t2;
                l_r[r] *= al;
#pragma unroll
                for (int dt = 0; dt < 4; ++dt) O[dt][r] *= al;
            }
        }

        // p-pass: accumulate per-lane l partials; NO per-tile shuffle reduce
#pragma unroll
        for (int nt = 0; nt < 8; ++nt)
#pragma unroll
            for (int r = 0; r < 4; ++r) {
                float p = EXP2(sacc[nt][r] - mn[r]);
                l_r[r] += p;
                Pw[(quad * 4 + r) * 136 + nt * 16 + lr] = f2bf_fast(p);
            }

        __builtin_amdgcn_s_setprio(1);
#pragma unroll
        for (int ks2 = 0; ks2 < 4; ++ks2) {
            s16x8 ap = *(const s16x8*)(Pw + lr * 136 + ks2 * 32 + quad * 8);
#pragma unroll
            for (int dt = 0; dt < 4; ++dt) {
                int d = dt * 16 + lr;
                s16x8 vb = *(const s16x8*)(Vs + d * 128 + (((ks2 * 4 + quad) + d) & 15) * 8);
                O[dt] = __builtin_amdgcn_mfma_f32_16x16x32_bf16(ap, vb, O[dt], 0, 0, 0);
            }
        }
        __builtin_amdgcn_s_setprio(0);
    }

    // final cross-lane reduce of the deferred l partials (once, not per tile)
#pragma unroll
    for (int msk = 1; msk <= 8; msk <<= 1)
#pragma unroll
        for (int r = 0; r < 4; ++r) l_r[r] += __shfl_xor(l_r[r], msk, 64);

    float rL[4];
#pragma unroll
    for (int r = 0; r < 4; ++r) rL[r] = 1.0f / l_r[r];
#pragma unroll
    for (int dt = 0; dt < 4; ++dt)
#pragma unroll
        for (int r = 0; r < 4; ++r) {
            int i = wrow0 + quad * 4 + r;
            av[(size_t)(i * 2 + b) * DM + n * 64 + dt * 16 + lr] = f2bf(O[dt][r] * rL[r]);
        }
}

// ---------------- fused split-K reduce + bias + residual + LayerNorm ----------------
// float4-ized (G13) — one pass of 16B/lane loads/stores.
__global__ __launch_bounds__(256) void ln_fused_k(
    const float* __restrict__ x1, const float* __restrict__ P,
    const float* __restrict__ bias,
    const float* __restrict__ gw, const float* __restrict__ bw,
    float* __restrict__ outf, u16* __restrict__ outb, int mode) {
    const int row = blockIdx.x, t = threadIdx.x, lane = t & 63, wv = t >> 6;
    const size_t MN = (size_t)QL * BATCH * DM;
    __shared__ float red[8];
    const int c0 = t * 4;
    const size_t base = (size_t)row * DM + c0;

    float4 a  = *(const float4*)(x1 + base);
    float4 p0 = *(const float4*)(P + base);
    float4 p1 = *(const float4*)(P + MN + base);
    float4 x;
    x.x = a.x + p0.x + p1.x;
    x.y = a.y + p0.y + p1.y;
    x.z = a.z + p0.z + p1.z;
    x.w = a.w + p0.w + p1.w;
    if (bias) {
        float4 bv = *(const float4*)(bias + c0);
        x.x += bv.x; x.y += bv.y; x.z += bv.z; x.w += bv.w;
    }
    float s  = x.x + x.y + x.z + x.w;
    float s2 = x.x * x.x + x.y * x.y + x.z * x.z + x.w * x.w;

#pragma unroll
    for (int o = 32; o; o >>= 1) {
        s  += __shfl_xor(s, o, 64);
        s2 += __shfl_xor(s2, o, 64);
    }
    if (lane == 0) { red[wv] = s; red[4 + wv] = s2; }
    __syncthreads();
    s  = red[0] + red[1] + red[2] + red[3];
    s2 = red[4] + red[5] + red[6] + red[7];
    float mean = s * (1.0f / DM);
    float var  = s2 * (1.0f / DM) - mean * mean;
    float rstd = rsqrtf(var + 1e-5f);

    float4 g  = *(const float4*)(gw + c0);
    float4 bb = *(const float4*)(bw + c0);
    float4 y;
    y.x = g.x * (x.x - mean) * rstd + bb.x;
    y.y = g.y * (x.y - mean) * rstd + bb.y;
    y.z = g.z * (x.z - mean) * rstd + bb.z;
    y.w = g.w * (x.w - mean) * rstd + bb.w;
    if (mode & 1) *(float4*)(outf + base) = y;
    if (mode & 2) {
        ushort4 o = {f2bf(y.x), f2bf(y.y), f2bf(y.z), f2bf(y.w)};
        *(ushort4*)(outb + base) = o;
    }
}

extern "C" void kernel_launch(void* const* d_in, const int* in_sizes, int n_in,
                              void* d_out, int out_size, void* d_ws, size_t ws_size,
                              hipStream_t stream) {
    const float* w        = (const float*)d_in[0];
    const float* mems     = (const float*)d_in[1];
    const float* r_emb    = (const float*)d_in[2];
    const float* r_w_bias = (const float*)d_in[3];
    const float* r_bias   = (const float*)d_in[4];
    const float* qkv_w    = (const float*)d_in[5];
    const float* o_w      = (const float*)d_in[6];
    const float* ln1_g    = (const float*)d_in[7];
    const float* ln1_b    = (const float*)d_in[8];
    const float* ff_w1    = (const float*)d_in[9];
    const float* ff_b1    = (const float*)d_in[10];
    const float* ff_w2    = (const float*)d_in[11];
    const float* ff_b2    = (const float*)d_in[12];
    const float* ln2_g    = (const float*)d_in[13];
    const float* ln2_b    = (const float*)d_in[14];
    float* out = (float*)d_out;

    char* ws = (char*)d_ws;
    size_t off = 0;
    auto alloc = [&](size_t bytes) {
        size_t o = off;
        off += (bytes + 255) & ~(size_t)255;
        return o;
    };
    u16* cat_bf   = (u16*)(ws + alloc((size_t)KL * BATCH * DM * 2));  // unused (kept for layout stability)
    u16* qkvw_bf  = (u16*)(ws + alloc((size_t)3 * NH * DH * DM * 2));
    u16* ow_bf    = (u16*)(ws + alloc((size_t)DM * NH * DH * 2));
    u16* w1_bf    = (u16*)(ws + alloc((size_t)DI * DM * 2));
    u16* w2_bf    = (u16*)(ws + alloc((size_t)DM * DI * 2));
    u16* rh_bf    = (u16*)(ws + alloc((size_t)NH * RPAD * 64 * 2));
    float* rb2    = (float*)(ws + alloc((size_t)NH * RPAD * 4));
    u16* Qb_bf    = (u16*)(ws + alloc((size_t)BATCH * QL * 1024 * 2));
    u16* Kh_bf    = (u16*)(ws + alloc((size_t)32 * 16 * 8192 * 2));   // 8 MB
    u16* Vt2_bf   = (u16*)(ws + alloc((size_t)32 * 16 * 8192 * 2));   // 8 MB (contig)
    u16* av_bf    = (u16*)(ws + alloc((size_t)QL * BATCH * DM * 2));
    float* h_f    = (float*)(ws + alloc((size_t)QL * BATCH * DM * 4));
    u16* h_bf     = (u16*)(ws + alloc((size_t)QL * BATCH * DM * 2));
    u16* inner_bf = (u16*)(ws + alloc((size_t)QL * BATCH * DI * 2));
    (void)ws_size; (void)in_sizes; (void)n_in; (void)out_size; (void)cat_bf;

    // split-K partials (2 x 8 MB fp32) overlay the Kh/Vt2 region, which is
    // dead after flash_attn completes (stream-ordered).
    float* Pk = (float*)Kh_bf;

    // 1) conversions + rel-bias prep (cvt_cat eliminated — fused into QKV A-staging)
    cvt_multi<<<2048, 256, 0, stream>>>(qkv_w, o_w, ff_w1, ff_w2,
                                        qkvw_bf, ow_bf, w1_bf, w2_bf);
    rcvt<<<dim3(72, 16), 256, 0, stream>>>(r_emb, rh_bf);
    rb2_prep<<<dim3(9, 16), 256, 0, stream>>>(r_emb, r_w_bias, r_bias, rb2);

    // 2) QKV projection, fused fp32->bf16 A-staging (FLAGS 8|16)
    gemm_s<128, 8 | 16><<<dim3(3072 / 128, (KL * BATCH) / 128), 256, 0, stream>>>(
        nullptr, qkvw_bf, nullptr, nullptr, Qb_bf, Kh_bf, Vt2_bf, nullptr,
        mems, w, KL * BATCH, 3072, DM);

    // 3) flash attention
    flash_attn<<<512, 256, 0, stream>>>(Qb_bf, Kh_bf, Vt2_bf, rh_bf,
                                        r_w_bias, rb2, av_bf);

    // 4) output projection, split-K x2 -> fp32 partials (2 blocks/CU)
    gemm_sk<2><<<dim3(DM / 64, (QL * BATCH) / 128, 2), 256, 0, stream>>>(
        av_bf, ow_bf, Pk, QL * BATCH, DM, DM);

    // 5) h = LN(w + P0 + P1)
    ln_fused_k<<<QL * BATCH, 256, 0, stream>>>(w, Pk, nullptr, ln1_g, ln1_b,
                                               h_f, h_bf, 3);

    // 6) inner = relu(h * ff_w1^T + b1)
    gemm_s<128, 1 | 2 | 4><<<dim3(DI / 128, (QL * BATCH) / 128), 256, 0, stream>>>(
        h_bf, w1_bf, nullptr, inner_bf, nullptr, nullptr, nullptr, ff_b1,
        nullptr, nullptr, QL * BATCH, DI, DM);

    // 7) ff_out partials, split-K x2 (K=2048 each, 2 blocks/CU)
    gemm_sk<2><<<dim3(DM / 64, (QL * BATCH) / 128, 2), 256, 0, stream>>>(
        inner_bf, w2_bf, Pk, QL * BATCH, DM, DI);

    // 8) out = LN(h + P0 + P1 + b2)
    ln_fused_k<<<QL * BATCH, 256, 0, stream>>>(h_f, Pk, ff_b2, ln2_g, ln2_b,
                                               out, nullptr, 1);
}

// Round 13
// 311.482 us; speedup vs baseline: 1.0686x; 1.0686x over previous
//
#include <hip/hip_runtime.h>
#include <math.h>

#define DM    1024
#define NH    16
#define DH    64
#define DI    4096
#define QL    1024
#define MLN   1024
#define BATCH 2
#define KL    2048   // QL + MLN
#define RPAD  2304   // padded jj extent for rh / rb2

// attention scale folded with log2(e) so softmax uses raw v_exp_f32 (2^x)
#define SCALE_LOG2E 0.18033688011112042f   // 0.125 * log2(e)

typedef unsigned short u16;
typedef short s16x8 __attribute__((ext_vector_type(8)));
typedef float f32x4 __attribute__((ext_vector_type(4)));

#if __has_builtin(__builtin_amdgcn_exp2f)
#define EXP2(x) __builtin_amdgcn_exp2f(x)
#else
#define EXP2(x) __expf((x) * 0.6931471805599453f)
#endif

__device__ __forceinline__ u16 f2bf(float f) {
    union { float f; unsigned u; } v; v.f = f;
    unsigned u = v.u;
    unsigned r = (u + 0x7FFFu + ((u >> 16) & 1u)) >> 16;
    return (u16)r;
}
__device__ __forceinline__ u16 f2bf_fast(float f) {
    union { float f; unsigned u; } v; v.f = f;
    return (u16)((v.u + 0x8000u) >> 16);
}
__device__ __forceinline__ float bf2f(u16 h) {
    union { unsigned u; float f; } v; v.u = ((unsigned)h) << 16;
    return v.f;
}

__device__ __forceinline__ void gl2lds16(const void* g, void* l) {
    __builtin_amdgcn_global_load_lds(
        (const __attribute__((address_space(1))) void*)g,
        (__attribute__((address_space(3))) void*)l, 16, 0, 0);
}

// ---------------- fused fp32->bf16: cat staging + all weights (one launch) ----
// Index space: [0, 1048576) = cat (batch-major re-layout of mems|w),
// [1048576, 4194304) = qkv_w / o_w / ff_w1 / ff_w2 straight conversion.
__global__ __launch_bounds__(256) void cvt_all(
    const float* __restrict__ mems, const float* __restrict__ w,
    const float* __restrict__ a0, const float* __restrict__ a1,
    const float* __restrict__ a2, const float* __restrict__ a3,
    u16* __restrict__ cat,
    u16* __restrict__ o0, u16* __restrict__ o1,
    u16* __restrict__ o2, u16* __restrict__ o3) {
    int i = blockIdx.x * 256 + threadIdx.x;
    int stride = gridDim.x * 256;
    for (; i < 4194304; i += stride) {
        if (i < 1048576) {
            int c4 = (i & 255) * 4;
            int row = i >> 8;
            int b = row >> 11, kpos = row & 2047;
            const float* src = (kpos < QL)
                ? mems + ((size_t)kpos * BATCH + b) * DM + c4
                : w + ((size_t)(kpos - QL) * BATCH + b) * DM + c4;
            float4 v = *(const float4*)src;
            ushort4 o = {f2bf(v.x), f2bf(v.y), f2bf(v.z), f2bf(v.w)};
            *(ushort4*)(cat + (size_t)row * DM + c4) = o;
        } else {
            int j = i - 1048576;
            const float* src; u16* dst; int k;
            if (j < 786432)       { src = a0; dst = o0; k = j; }
            else if (j < 1048576) { src = a1; dst = o1; k = j - 786432; }
            else if (j < 2097152) { src = a2; dst = o2; k = j - 1048576; }
            else                  { src = a3; dst = o3; k = j - 2097152; }
            float4 v = ((const float4*)src)[k];
            ushort4 o = {f2bf(v.x), f2bf(v.y), f2bf(v.z), f2bf(v.w)};
            ((ushort4*)dst)[k] = o;
        }
    }
}

// rh[n][jj][64d], granule-swizzled: stored granule gs holds logical granule
// gl=(gs-jj)&7 (16B granules). jj>=KL -> zeros. grid dim3(72,16).
// Round-13: also computes rb2[n][jj] in-flight — each 8-thread (n,jj) group
// holds exactly the 64 r_emb values the dot needs; 3-step shfl_xor reduce
// (groups are 8-aligned within the wave), lane gs==0 writes.
__global__ __launch_bounds__(256) void rcvt(const float* __restrict__ r_emb,
                                            const float* __restrict__ r_w_bias,
                                            const float* __restrict__ r_bias,
                                            u16* __restrict__ rh,
                                            float* __restrict__ rb2) {
    int id = blockIdx.x * 256 + threadIdx.x;
    int n = blockIdx.y;
    int jj = id >> 3, gs = id & 7;
    s16x8 o;
    float part = 0.0f;
    if (jj < KL) {
        int gl = (gs - jj) & 7;
        const float* s = r_emb + (size_t)jj * DM + n * 64 + gl * 8;
#pragma unroll
        for (int k = 0; k < 8; ++k) {
            float f = s[k];
            o[k] = (short)f2bf(f);
            part += r_w_bias[n * 64 + gl * 8 + k] * f;
        }
    } else {
#pragma unroll
        for (int k = 0; k < 8; ++k) o[k] = 0;
    }
    *(s16x8*)(rh + ((size_t)n * RPAD + jj) * 64 + gs * 8) = o;

    part += __shfl_xor(part, 1, 64);
    part += __shfl_xor(part, 2, 64);
    part += __shfl_xor(part, 4, 64);
    if (gs == 0) {
        float v = 0.0f;
        if (jj < KL) v = SCALE_LOG2E * (r_bias[jj * NH + n] - part);
        rb2[n * RPAD + jj] = v;
    }
}

// ---------------- staged GEMM: C[M,*] = A[M,K] * B[*,K]^T ----------------
// T3-minimum 2-phase pipeline — double-buffered As/Bs, stage(t+1) issued
// BEFORE compute(t), ONE barrier per K-step. Staging hides under MFMA work.
// FLAGS: 1=bf16 out, 2=bias, 4=relu, 8=QKV split epilogue (Q/Kh/Vt2 layouts)
// (Round-12's fused-cvt A-staging REVERTED: A-tiles are re-staged once per
// n-block, so fused conversion repeats 24x -> +29 µs. Reuse-factor lesson.)
template <int BN, int FLAGS>
__global__ __launch_bounds__(256) void gemm_s(const u16* __restrict__ A,
                                              const u16* __restrict__ B,
                                              float* __restrict__ Cf,
                                              u16* __restrict__ Cb,
                                              u16* __restrict__ Qo,
                                              u16* __restrict__ Ko,
                                              u16* __restrict__ Vo,
                                              const float* __restrict__ bias,
                                              int M, int N_out, int K) {
    constexpr int WN = BN / 2;
    constexpr int TN = WN / 16;

    if constexpr (FLAGS & 8) {
        // dead-block skip: Q columns (n_blk<8) x mems rows ((y&15)<8) store
        // nothing -> 128/768 blocks, -16.7%.
        if (blockIdx.x < 8 && (blockIdx.y & 15) < 8) return;
    }

    __shared__ u16 As[2][128 * 32];
    __shared__ u16 Bs[2][BN * 32];

    const int t = threadIdx.x;
    const int lane = t & 63, wid = t >> 6;
    const int wm = wid >> 1, wn = wid & 1;
    const int lr = lane & 15, quad = lane >> 4;
    const int m_blk = blockIdx.y * 128;
    const int n_blk = blockIdx.x * BN;
    const int srow = t >> 2;
    const int skc  = (t & 3) * 8;

    f32x4 acc[4][TN];
#pragma unroll
    for (int i = 0; i < 4; ++i)
#pragma unroll
        for (int j = 0; j < TN; ++j) acc[i][j] = (f32x4)0.0f;

    auto stage = [&](int bf, int k0) {
        gl2lds16(A + (size_t)(m_blk + srow) * K + k0 + skc, &As[bf][wid * 512]);
        gl2lds16(A + (size_t)(m_blk + 64 + srow) * K + k0 + skc, &As[bf][2048 + wid * 512]);
        gl2lds16(B + (size_t)(n_blk + srow) * K + k0 + skc, &Bs[bf][wid * 512]);
        if (BN == 128)
            gl2lds16(B + (size_t)(n_blk + 64 + srow) * K + k0 + skc, &Bs[bf][2048 + wid * 512]);
    };

    stage(0, 0);
    __syncthreads();   // drains vmcnt: buf0 staged

    int cur = 0;
    for (int k0 = 0; k0 < K; k0 += 32) {
        if (k0 + 32 < K) stage(cur ^ 1, k0 + 32);

        s16x8 a[4], b[TN];
#pragma unroll
        for (int i = 0; i < 4; ++i)
            a[i] = *(const s16x8*)(&As[cur][(wm * 64 + i * 16 + lr) * 32 + quad * 8]);
#pragma unroll
        for (int j = 0; j < TN; ++j)
            b[j] = *(const s16x8*)(&Bs[cur][(wn * WN + j * 16 + lr) * 32 + quad * 8]);
#pragma unroll
        for (int i = 0; i < 4; ++i)
#pragma unroll
            for (int j = 0; j < TN; ++j)
                acc[i][j] = __builtin_amdgcn_mfma_f32_16x16x32_bf16(
                    a[i], b[j], acc[i][j], 0, 0, 0);

        __syncthreads();   // staging(t+1) landed; all waves done with buf[cur]
        cur ^= 1;
    }

#pragma unroll
    for (int i = 0; i < 4; ++i) {
#pragma unroll
        for (int j = 0; j < TN; ++j) {
            int row0 = m_blk + wm * 64 + i * 16 + quad * 4;
            int col  = n_blk + wn * WN + j * 16 + lr;
            if (FLAGS & 8) {
                int b_ = row0 >> 11, kpos = row0 & 2047;
                if (col < 1024) {
                    if (kpos >= QL) {
                        u16* q = Qo + ((size_t)(b_ * QL + kpos - QL)) * 1024 + col;
#pragma unroll
                        for (int r = 0; r < 4; ++r) q[r * 1024] = f2bf(acc[i][j][r]);
                    }
                } else if (col < 2048) {
                    int d = col & 63, nh = (col >> 6) & 15;
                    size_t base = ((size_t)((b_ * 16 + nh) * 16 + (kpos >> 7))) * 8192;
#pragma unroll
                    for (int r = 0; r < 4; ++r) {
                        int jl = (kpos & 127) + r;
                        Ko[base + jl * 64 + (((d >> 3) + jl) & 7) * 8 + (d & 7)] =
                            f2bf(acc[i][j][r]);
                    }
                } else {
                    int d = col & 63, nh = (col >> 6) & 15;
                    int jl = kpos & 127;
                    size_t base = ((size_t)((b_ * 16 + nh) * 16 + (kpos >> 7))) * 8192
                                  + d * 128 + (((jl >> 3) + d) & 15) * 8 + (jl & 7);
                    ushort4 o = {f2bf(acc[i][j][0]), f2bf(acc[i][j][1]),
                                 f2bf(acc[i][j][2]), f2bf(acc[i][j][3])};
                    *(ushort4*)(Vo + base) = o;
                }
            } else {
                float bv = (FLAGS & 2) ? bias[col] : 0.0f;
#pragma unroll
                for (int r = 0; r < 4; ++r) {
                    float v = acc[i][j][r] + bv;
                    if (FLAGS & 4) v = fmaxf(v, 0.0f);
                    size_t idx = (size_t)(row0 + r) * N_out + col;
                    if (FLAGS & 1) Cb[idx] = f2bf(v);
                    else           Cf[idx] = v;
                }
            }
        }
    }
}

// ---------------- split-K GEMM: P[kz][M,N] = A[M,Kc] * B[N,Kc]^T ----------------
// Same 2-phase double-buffer as gemm_s. grid (N/64, M/128, SPLIT).
template <int SPLIT>
__global__ __launch_bounds__(256) void gemm_sk(const u16* __restrict__ A,
                                               const u16* __restrict__ B,
                                               float* __restrict__ P,
                                               int M, int N_out, int K) {
    __shared__ u16 As[2][128 * 32];
    __shared__ u16 Bs[2][64 * 32];

    const int t = threadIdx.x;
    const int lane = t & 63, wid = t >> 6;
    const int wm = wid >> 1, wn = wid & 1;
    const int lr = lane & 15, quad = lane >> 4;
    const int m_blk = blockIdx.y * 128;
    const int n_blk = blockIdx.x * 64;
    const int kz = blockIdx.z;
    const int Kc = K / SPLIT;
    const int kbeg = kz * Kc, kend = kbeg + Kc;
    const int srow = t >> 2;
    const int skc  = (t & 3) * 8;

    f32x4 acc[4][2];
#pragma unroll
    for (int i = 0; i < 4; ++i)
#pragma unroll
        for (int j = 0; j < 2; ++j) acc[i][j] = (f32x4)0.0f;

    auto stage = [&](int bf, int k0) {
        gl2lds16(A + (size_t)(m_blk + srow) * K + k0 + skc, &As[bf][wid * 512]);
        gl2lds16(A + (size_t)(m_blk + 64 + srow) * K + k0 + skc, &As[bf][2048 + wid * 512]);
        gl2lds16(B + (size_t)(n_blk + srow) * K + k0 + skc, &Bs[bf][wid * 512]);
    };

    stage(0, kbeg);
    __syncthreads();

    int cur = 0;
    for (int k0 = kbeg; k0 < kend; k0 += 32) {
        if (k0 + 32 < kend) stage(cur ^ 1, k0 + 32);

        s16x8 a[4], b[2];
#pragma unroll
        for (int i = 0; i < 4; ++i)
            a[i] = *(const s16x8*)(&As[cur][(wm * 64 + i * 16 + lr) * 32 + quad * 8]);
#pragma unroll
        for (int j = 0; j < 2; ++j)
            b[j] = *(const s16x8*)(&Bs[cur][(wn * 32 + j * 16 + lr) * 32 + quad * 8]);
#pragma unroll
        for (int i = 0; i < 4; ++i)
#pragma unroll
            for (int j = 0; j < 2; ++j)
                acc[i][j] = __builtin_amdgcn_mfma_f32_16x16x32_bf16(
                    a[i], b[j], acc[i][j], 0, 0, 0);

        __syncthreads();
        cur ^= 1;
    }

    float* Pz = P + (size_t)kz * M * N_out;
#pragma unroll
    for (int i = 0; i < 4; ++i)
#pragma unroll
        for (int j = 0; j < 2; ++j) {
            int row0 = m_blk + wm * 64 + i * 16 + quad * 4;
            int col  = n_blk + wn * 32 + j * 16 + lr;
#pragma unroll
            for (int r = 0; r < 4; ++r)
                Pz[(size_t)(row0 + r) * N_out + col] = acc[i][j][r];
        }
}

// ---------------- flash attention ----------------
// BYTE-IDENTICAL to the round-8/11 kernel (57-59 µs). Staged-uniform gl2lds
// for R/K/V is the proven structure; R-direct and split-j both regressed.
__global__ __launch_bounds__(256, 2) void flash_attn(
    const u16* __restrict__ Qb, const u16* __restrict__ Kh,
    const u16* __restrict__ Vt2, const u16* __restrict__ rh,
    const float* __restrict__ r_w_bias, const float* __restrict__ rb2,
    u16* __restrict__ av) {
    const int bid = blockIdx.x;
    const int x = bid & 7;            // XCD (round-robin dispatch)
    const int s = bid >> 3;           // 0..63 sequence on this XCD
    const int half = s >> 5;          // 0/1 (CU c gets s=c and s=c+32)
    const int r_ = s & 31;
    const int bnl = (r_ >> 4) + 2 * half;   // 0..3
    const int bn = x + 8 * bnl;             // bn ≡ x (mod 8): XCD-local
    const int p_ = r_ & 15;
    const int ti = half ? (15 - p_) : p_;   // pair (p,15-p): 25 tiles/CU
    const int i0 = ti * 64;
    const int b = bn >> 4, n = bn & 15;
    const int t = threadIdx.x;
    const int lane = t & 63, w = t >> 6;
    const int lr = lane & 15, quad = lane >> 4;

    __shared__ __align__(16) u16 Ks[128 * 64];
    __shared__ __align__(16) u16 Vs[64 * 128];
    __shared__ __align__(16) u16 Rs[192 * 64];
    __shared__ __align__(16) u16 Pw_all[4 * 16 * 136];
    u16* Pw = Pw_all + w * (16 * 136);

    const int wrow0 = i0 + w * 16;

    s16x8 qw[2];
#pragma unroll
    for (int ks = 0; ks < 2; ++ks) {
        const u16* qp = Qb + ((size_t)(b * QL + wrow0 + lr)) * 1024 + n * 64 + ks * 32 + quad * 8;
        s16x8 qv = *(const s16x8*)qp;
        s16x8 o;
#pragma unroll
        for (int k = 0; k < 8; ++k) {
            float f = bf2f((u16)qv[k]) + r_w_bias[n * 64 + ks * 32 + quad * 8 + k];
            o[k] = (short)f2bf(f * SCALE_LOG2E);
        }
        qw[ks] = o;
    }

    f32x4 O[4];
    float m_r[4], l_r[4];
#pragma unroll
    for (int xx = 0; xx < 4; ++xx) {
        O[xx] = (f32x4)0.0f;
        m_r[xx] = -INFINITY;
        l_r[xx] = 0.0f;
    }

    const u16* Kt0 = Kh + (size_t)bn * 16 * 8192;
    const u16* Vt0 = Vt2 + (size_t)bn * 16 * 8192;
    const u16* Rbase = rh + (size_t)n * RPAD * 64;
    const int jend = i0 + 64 + MLN;

    // prologue: prefetch R for tile 0
    {
        const u16* Rsrc = Rbase + (size_t)(960 - i0) * 64;
#pragma unroll
        for (int k = 0; k < 6; ++k)
            gl2lds16(Rsrc + (w * 6 + k) * 512 + lane * 8, Rs + (w * 6 + k) * 512);
    }

    for (int j0 = 0; j0 < jend; j0 += 128) {
        const int jjbase_blk = j0 + 960 - i0;
        __syncthreads();   // R(t) landed; prev tile's Ks/Vs/Pw fully consumed
        {
            const u16* Ksrc = Kt0 + (size_t)(j0 >> 7) * 8192;
            const u16* Vsrc = Vt0 + (size_t)(j0 >> 7) * 8192;
#pragma unroll
            for (int k = 0; k < 4; ++k)
                gl2lds16(Ksrc + (w * 4 + k) * 512 + lane * 8, Ks + (w * 4 + k) * 512);
#pragma unroll
            for (int k = 0; k < 4; ++k)
                gl2lds16(Vsrc + (w * 4 + k) * 512 + lane * 8, Vs + (w * 4 + k) * 512);
        }

        // rel-pos term from Rs (LDS); K/V loads in flight underneath.
        f32x4 bacc[9];
#pragma unroll
        for (int c = 0; c < 9; ++c) bacc[c] = (f32x4)0.0f;
#pragma unroll
        for (int ks = 0; ks < 2; ++ks) {
#pragma unroll
            for (int c = 0; c < 9; ++c) {
                int row = c * 16 + lr + 48 - 16 * w;
                s16x8 rf = *(const s16x8*)(Rs + row * 64 + (((ks * 4 + quad) + row) & 7) * 8);
                bacc[c] = __builtin_amdgcn_mfma_f32_16x16x32_bf16(qw[ks], rf, bacc[c], 0, 0, 0);
            }
        }
#pragma unroll
        for (int c = 0; c < 9; ++c) {
            int jj = jjbase_blk + 48 - 16 * w + c * 16 + lr;
            float rv = rb2[n * RPAD + jj];
            bacc[c][0] += rv; bacc[c][1] += rv; bacc[c][2] += rv; bacc[c][3] += rv;
        }
        f32x4 sacc[8];
#pragma unroll
        for (int r = 0; r < 4; ++r) {
            int rho = quad * 4 + r;
            int lrt_src = (lr + rho + 1) & 15;
            int up = lrt_src > rho;
            int addr = (((lane & 48) | ((lr + 15 - rho) & 15)) << 2);
#pragma unroll
            for (int nt = 0; nt < 8; ++nt) {
                float v = up ? bacc[nt + 1][r] : bacc[nt][r];
                sacc[nt][r] = __int_as_float(
                    __builtin_amdgcn_ds_bpermute(addr, __float_as_int(v)));
            }
        }

        __syncthreads();   // K/V staged; all waves past bacc -> Rs dead

        // prefetch R for next tile; drains at next tile's sync1
        if (j0 + 128 < jend) {
            const u16* Rsrc = Rbase + (size_t)(jjbase_blk + 128) * 64;
#pragma unroll
            for (int k = 0; k < 6; ++k)
                gl2lds16(Rsrc + (w * 6 + k) * 512 + lane * 8, Rs + (w * 6 + k) * 512);
        }

        __builtin_amdgcn_s_setprio(1);
#pragma unroll
        for (int ks = 0; ks < 2; ++ks) {
#pragma unroll
            for (int nt = 0; nt < 8; ++nt) {
                int jloc = nt * 16 + lr;
                s16x8 kf = *(const s16x8*)(Ks + jloc * 64 + (((ks * 4 + quad) + jloc) & 7) * 8);
                sacc[nt] = __builtin_amdgcn_mfma_f32_16x16x32_bf16(qw[ks], kf, sacc[nt], 0, 0, 0);
            }
        }
        __builtin_amdgcn_s_setprio(0);

        if (j0 + 127 > i0 + MLN) {   // only the last j-tile crosses the causal edge
#pragma unroll
            for (int nt = 0; nt < 8; ++nt) {
                int j = j0 + nt * 16 + lr;
#pragma unroll
                for (int r = 0; r < 4; ++r) {
                    int i = wrow0 + quad * 4 + r;
                    if (j > i + MLN) sacc[nt][r] = -INFINITY;
                }
            }
        }

        // conservative gate: lane-local max (VALU only)
        float maxall = sacc[0][0];
#pragma unroll
        for (int nt = 0; nt < 8; ++nt)
#pragma unroll
            for (int r = 0; r < 4; ++r) maxall = fmaxf(maxall, sacc[nt][r]);
        float mmin = fminf(fminf(m_r[0], m_r[1]), fminf(m_r[2], m_r[3]));

        float mn[4];
        if (__all(maxall <= mmin + 8.0f)) {
#pragma unroll
            for (int r = 0; r < 4; ++r) mn[r] = m_r[r];
        } else {
            float mx[4];
#pragma unroll
            for (int r = 0; r < 4; ++r) {
                mx[r] = sacc[0][r];
#pragma unroll
                for (int nt = 1; nt < 8; ++nt) mx[r] = fmaxf(mx[r], sacc[nt][r]);
            }
#pragma unroll
            for (int msk = 1; msk <= 8; msk <<= 1)
#pragma unroll
                for (int r = 0; r < 4; ++r)
                    mx[r] = fmaxf(mx[r], __shfl_xor(mx[r], msk, 64));
#pragma unroll
            for (int r = 0; r < 4; ++r) {
                float t2 = fmaxf(m_r[r], mx[r]);
                float al = EXP2(m_r[r] - t2);
                m_r[r] = t2; mn[r] = t2;
                l_r[r] *= al;
#pragma unroll
                for (int dt = 0; dt < 4; ++dt) O[dt][r] *= al;
            }
        }

        // p-pass: accumulate per-lane l partials; NO per-tile shuffle reduce
#pragma unroll
        for (int nt = 0; nt < 8; ++nt)
#pragma unroll
            for (int r = 0; r < 4; ++r) {
                float p = EXP2(sacc[nt][r] - mn[r]);
                l_r[r] += p;
                Pw[(quad * 4 + r) * 136 + nt * 16 + lr] = f2bf_fast(p);
            }

        __builtin_amdgcn_s_setprio(1);
#pragma unroll
        for (int ks2 = 0; ks2 < 4; ++ks2) {
            s16x8 ap = *(const s16x8*)(Pw + lr * 136 + ks2 * 32 + quad * 8);
#pragma unroll
            for (int dt = 0; dt < 4; ++dt) {
                int d = dt * 16 + lr;
                s16x8 vb = *(const s16x8*)(Vs + d * 128 + (((ks2 * 4 + quad) + d) & 15) * 8);
                O[dt] = __builtin_amdgcn_mfma_f32_16x16x32_bf16(ap, vb, O[dt], 0, 0, 0);
            }
        }
        __builtin_amdgcn_s_setprio(0);
    }

    // final cross-lane reduce of the deferred l partials (once, not per tile)
#pragma unroll
    for (int msk = 1; msk <= 8; msk <<= 1)
#pragma unroll
        for (int r = 0; r < 4; ++r) l_r[r] += __shfl_xor(l_r[r], msk, 64);

    float rL[4];
#pragma unroll
    for (int r = 0; r < 4; ++r) rL[r] = 1.0f / l_r[r];
#pragma unroll
    for (int dt = 0; dt < 4; ++dt)
#pragma unroll
        for (int r = 0; r < 4; ++r) {
            int i = wrow0 + quad * 4 + r;
            av[(size_t)(i * 2 + b) * DM + n * 64 + dt * 16 + lr] = f2bf(O[dt][r] * rL[r]);
        }
}

// ---------------- fused split-K reduce + bias + residual + LayerNorm ----------------
// float4-ized (G13) — one pass of 16B/lane loads/stores.
__global__ __launch_bounds__(256) void ln_fused_k(
    const float* __restrict__ x1, const float* __restrict__ P,
    const float* __restrict__ bias,
    const float* __restrict__ gw, const float* __restrict__ bw,
    float* __restrict__ outf, u16* __restrict__ outb, int mode) {
    const int row = blockIdx.x, t = threadIdx.x, lane = t & 63, wv = t >> 6;
    const size_t MN = (size_t)QL * BATCH * DM;
    __shared__ float red[8];
    const int c0 = t * 4;
    const size_t base = (size_t)row * DM + c0;

    float4 a  = *(const float4*)(x1 + base);
    float4 p0 = *(const float4*)(P + base);
    float4 p1 = *(const float4*)(P + MN + base);
    float4 x;
    x.x = a.x + p0.x + p1.x;
    x.y = a.y + p0.y + p1.y;
    x.z = a.z + p0.z + p1.z;
    x.w = a.w + p0.w + p1.w;
    if (bias) {
        float4 bv = *(const float4*)(bias + c0);
        x.x += bv.x; x.y += bv.y; x.z += bv.z; x.w += bv.w;
    }
    float s  = x.x + x.y + x.z + x.w;
    float s2 = x.x * x.x + x.y * x.y + x.z * x.z + x.w * x.w;

#pragma unroll
    for (int o = 32; o; o >>= 1) {
        s  += __shfl_xor(s, o, 64);
        s2 += __shfl_xor(s2, o, 64);
    }
    if (lane == 0) { red[wv] = s; red[4 + wv] = s2; }
    __syncthreads();
    s  = red[0] + red[1] + red[2] + red[3];
    s2 = red[4] + red[5] + red[6] + red[7];
    float mean = s * (1.0f / DM);
    float var  = s2 * (1.0f / DM) - mean * mean;
    float rstd = rsqrtf(var + 1e-5f);

    float4 g  = *(const float4*)(gw + c0);
    float4 bb = *(const float4*)(bw + c0);
    float4 y;
    y.x = g.x * (x.x - mean) * rstd + bb.x;
    y.y = g.y * (x.y - mean) * rstd + bb.y;
    y.z = g.z * (x.z - mean) * rstd + bb.z;
    y.w = g.w * (x.w - mean) * rstd + bb.w;
    if (mode & 1) *(float4*)(outf + base) = y;
    if (mode & 2) {
        ushort4 o = {f2bf(y.x), f2bf(y.y), f2bf(y.z), f2bf(y.w)};
        *(ushort4*)(outb + base) = o;
    }
}

extern "C" void kernel_launch(void* const* d_in, const int* in_sizes, int n_in,
                              void* d_out, int out_size, void* d_ws, size_t ws_size,
                              hipStream_t stream) {
    const float* w        = (const float*)d_in[0];
    const float* mems     = (const float*)d_in[1];
    const float* r_emb    = (const float*)d_in[2];
    const float* r_w_bias = (const float*)d_in[3];
    const float* r_bias   = (const float*)d_in[4];
    const float* qkv_w    = (const float*)d_in[5];
    const float* o_w      = (const float*)d_in[6];
    const float* ln1_g    = (const float*)d_in[7];
    const float* ln1_b    = (const float*)d_in[8];
    const float* ff_w1    = (const float*)d_in[9];
    const float* ff_b1    = (const float*)d_in[10];
    const float* ff_w2    = (const float*)d_in[11];
    const float* ff_b2    = (const float*)d_in[12];
    const float* ln2_g    = (const float*)d_in[13];
    const float* ln2_b    = (const float*)d_in[14];
    float* out = (float*)d_out;

    char* ws = (char*)d_ws;
    size_t off = 0;
    auto alloc = [&](size_t bytes) {
        size_t o = off;
        off += (bytes + 255) & ~(size_t)255;
        return o;
    };
    u16* cat_bf   = (u16*)(ws + alloc((size_t)KL * BATCH * DM * 2));
    u16* qkvw_bf  = (u16*)(ws + alloc((size_t)3 * NH * DH * DM * 2));
    u16* ow_bf    = (u16*)(ws + alloc((size_t)DM * NH * DH * 2));
    u16* w1_bf    = (u16*)(ws + alloc((size_t)DI * DM * 2));
    u16* w2_bf    = (u16*)(ws + alloc((size_t)DM * DI * 2));
    u16* rh_bf    = (u16*)(ws + alloc((size_t)NH * RPAD * 64 * 2));
    float* rb2    = (float*)(ws + alloc((size_t)NH * RPAD * 4));
    u16* Qb_bf    = (u16*)(ws + alloc((size_t)BATCH * QL * 1024 * 2));
    u16* Kh_bf    = (u16*)(ws + alloc((size_t)32 * 16 * 8192 * 2));   // 8 MB
    u16* Vt2_bf   = (u16*)(ws + alloc((size_t)32 * 16 * 8192 * 2));   // 8 MB (contig)
    u16* av_bf    = (u16*)(ws + alloc((size_t)QL * BATCH * DM * 2));
    float* h_f    = (float*)(ws + alloc((size_t)QL * BATCH * DM * 4));
    u16* h_bf     = (u16*)(ws + alloc((size_t)QL * BATCH * DM * 2));
    u16* inner_bf = (u16*)(ws + alloc((size_t)QL * BATCH * DI * 2));
    (void)ws_size; (void)in_sizes; (void)n_in; (void)out_size;

    // split-K partials (2 x 8 MB fp32) overlay the Kh/Vt2 region, which is
    // dead after flash_attn completes (stream-ordered).
    float* Pk = (float*)Kh_bf;

    // 1) conversions + rel-bias prep (cat + 4 weights in ONE launch;
    //    rb2 computed inside rcvt — two kernels removed vs round 11)
    cvt_all<<<2048, 256, 0, stream>>>(mems, w, qkv_w, o_w, ff_w1, ff_w2,
                                      cat_bf, qkvw_bf, ow_bf, w1_bf, w2_bf);
    rcvt<<<dim3(72, 16), 256, 0, stream>>>(r_emb, r_w_bias, r_bias, rh_bf, rb2);

    // 2) QKV projection with Q/Kh/Vt2 split epilogue (dead Q-blocks skipped)
    gemm_s<128, 8><<<dim3(3072 / 128, (KL * BATCH) / 128), 256, 0, stream>>>(
        cat_bf, qkvw_bf, nullptr, nullptr, Qb_bf, Kh_bf, Vt2_bf, nullptr,
        KL * BATCH, 3072, DM);

    // 3) flash attention
    flash_attn<<<512, 256, 0, stream>>>(Qb_bf, Kh_bf, Vt2_bf, rh_bf,
                                        r_w_bias, rb2, av_bf);

    // 4) output projection, split-K x2 -> fp32 partials (2 blocks/CU)
    gemm_sk<2><<<dim3(DM / 64, (QL * BATCH) / 128, 2), 256, 0, stream>>>(
        av_bf, ow_bf, Pk, QL * BATCH, DM, DM);

    // 5) h = LN(w + P0 + P1)
    ln_fused_k<<<QL * BATCH, 256, 0, stream>>>(w, Pk, nullptr, ln1_g, ln1_b,
                                               h_f, h_bf, 3);

    // 6) inner = relu(h * ff_w1^T + b1)
    gemm_s<128, 1 | 2 | 4><<<dim3(DI / 128, (QL * BATCH) / 128), 256, 0, stream>>>(
        h_bf, w1_bf, nullptr, inner_bf, nullptr, nullptr, nullptr, ff_b1,
        QL * BATCH, DI, DM);

    // 7) ff_out partials, split-K x2 (K=2048 each, 2 blocks/CU)
    gemm_sk<2><<<dim3(DM / 64, (QL * BATCH) / 128, 2), 256, 0, stream>>>(
        inner_bf, w2_bf, Pk, QL * BATCH, DM, DI);

    // 8) out = LN(h + P0 + P1 + b2)
    ln_fused_k<<<QL * BATCH, 256, 0, stream>>>(h_f, Pk, ff_b2, ln2_g, ln2_b,
                                               out, nullptr, 1);
}